// Round 6
// baseline (424.780 us; speedup 1.0000x reference)
//
#include <hip/hip_runtime.h>
#include <math.h>

// Problem constants (from reference): N slices of D x D matrices.
#define NSL 262144
#define D 16
#define NBLK (NSL / 256)  // 1024 partial sums

// r_matrix layout is [D, D, N] -> element (i,j) of slice n at (i*D+j)*N + n.
// One thread per slice: every load of a fixed (i,j) is perfectly coalesced
// across the wave (64 consecutive n -> one 256B aligned transaction).

// MEASUREMENT ROUND: loss_kernel is launched TWICE (idempotent, same
// partials written both times). dur_us(R6) - dur_us(R5) = one kernel
// duration K, cancelling the unknown per-iteration harness overhead
// (1GB ws poison + input restore) that dominates the timed window.

// Final reduce: 1024 doubles -> one float. One block of 256 threads.
__global__ void finalize_kernel(const double* __restrict__ partial,
                                float* __restrict__ out) {
    const int t = threadIdx.x;
    double c = (partial[t] + partial[t + 256]) +
               (partial[t + 512] + partial[t + 768]);
#pragma unroll
    for (int off = 32; off > 0; off >>= 1) c += __shfl_down(c, off, 64);
    __shared__ double wsum[4];
    const int lane = t & 63, wv = t >> 6;
    if (lane == 0) wsum[wv] = c;
    __syncthreads();
    if (t == 0) out[0] = (float)((wsum[0] + wsum[1]) + (wsum[2] + wsum[3]));
}

// Doolittle row-streaming LU (no pivoting; matrices are I + 0.1*noise,
// well-conditioned -> absmax was 0.0 vs reference). Only the upper triangle
// stays live; explicit next-row prefetch keeps 16 loads in flight during
// elimination (~215 VGPRs, 2 waves/SIMD).
__global__ __launch_bounds__(256, 2) void loss_kernel(
    const float* __restrict__ gamma,
    const float* __restrict__ exp_cpv,
    const float* __restrict__ rmat,
    double* __restrict__ partial) {
    const int n = blockIdx.x * blockDim.x + threadIdx.x;

    // diff = gamma[n,:] - exp_cpv[n,:]  (contiguous 64B per thread, float4 x4)
    float diff[D];
    {
        const float4* g4 = reinterpret_cast<const float4*>(gamma + (size_t)n * D);
        const float4* e4 = reinterpret_cast<const float4*>(exp_cpv + (size_t)n * D);
#pragma unroll
        for (int c = 0; c < 4; ++c) {
            float4 g = g4[c];
            float4 e = e4[c];
            diff[4 * c + 0] = g.x - e.x;
            diff[4 * c + 1] = g.y - e.y;
            diff[4 * c + 2] = g.z - e.z;
            diff[4 * c + 3] = g.w - e.w;
        }
    }

    const float* Rb = rmat + n;

    float U[D][D];   // only j > i entries stay live (upper triangle)
    float invd[D];   // 1 / u_kk
    float vsq = 0.0f;      // sum v_i^2 (matvec with ORIGINAL rows)
    float detprod = 1.0f;  // product of pivots

    float a[D];      // current row (original values on entry to iteration i)
    float nxt[D];    // prefetched next row
#pragma unroll
    for (int j = 0; j < D; ++j) a[j] = Rb[(size_t)j * NSL];

#pragma unroll
    for (int i = 0; i < D; ++i) {
        // Issue next row's loads FIRST so they overlap the elimination math.
        if (i < D - 1) {
#pragma unroll
            for (int j = 0; j < D; ++j)
                nxt[j] = Rb[(size_t)((i + 1) * D + j) * NSL];
        }

        // Matvec with the ORIGINAL row before elimination destroys it.
        float vi = 0.0f;
#pragma unroll
        for (int j = 0; j < D; ++j) vi += a[j] * diff[j];
        vsq += vi * vi;

        // Fold row i against previously finalized U rows 0..i-1.
#pragma unroll
        for (int k = 0; k < i; ++k) {
            float m = a[k] * invd[k];
#pragma unroll
            for (int j = k + 1; j < D; ++j) a[j] -= m * U[k][j];
        }

        // Row i finalized: pivot is a[i].
        detprod *= a[i];
        invd[i] = 1.0f / a[i];
#pragma unroll
        for (int j = i + 1; j < D; ++j) U[i][j] = a[j];

        if (i < D - 1) {
#pragma unroll
            for (int j = 0; j < D; ++j) a[j] = nxt[j];
        }
    }

    const float l2 = sqrtf(vsq);
    const float logabs = logf(fabsf(detprod));
    double c = (double)l2 - 2.0 * (double)logabs;

    // Wave (64-lane) reduction, then one plain store per block (no atomic,
    // no ws zero-init needed: finalize reads exactly the written slots).
#pragma unroll
    for (int off = 32; off > 0; off >>= 1) c += __shfl_down(c, off, 64);

    __shared__ double wsum[4];
    const int lane = threadIdx.x & 63;
    const int wv = threadIdx.x >> 6;
    if (lane == 0) wsum[wv] = c;
    __syncthreads();
    if (threadIdx.x == 0) {
        partial[blockIdx.x] = (wsum[0] + wsum[1]) + (wsum[2] + wsum[3]);
    }
}

extern "C" void kernel_launch(void* const* d_in, const int* in_sizes, int n_in,
                              void* d_out, int out_size, void* d_ws, size_t ws_size,
                              hipStream_t stream) {
    const float* gamma = (const float*)d_in[0];
    const float* exp_cpv = (const float*)d_in[1];
    const float* rmat = (const float*)d_in[2];
    float* out = (float*)d_out;
    double* partial = (double*)d_ws;

    // Launched twice on purpose: timing probe (see header comment).
    loss_kernel<<<NBLK, 256, 0, stream>>>(gamma, exp_cpv, rmat, partial);
    loss_kernel<<<NBLK, 256, 0, stream>>>(gamma, exp_cpv, rmat, partial);
    finalize_kernel<<<1, 256, 0, stream>>>(partial, out);
}

// Round 7
// 376.727 us; speedup vs baseline: 1.1276x; 1.1276x over previous
//
#include <hip/hip_runtime.h>
#include <math.h>

// Problem constants (from reference): N slices of D x D matrices.
#define NSL 262144
#define D 16
#define NBLK (NSL / 256)  // 1024 partial sums

// r_matrix layout is [D, D, N] -> element (i,j) of slice n at (i*D+j)*N + n.
// One thread per slice: every load of a fixed (i,j) is perfectly coalesced
// across the wave (64 consecutive n -> one 256B aligned transaction).
//
// MEASURED (R5 vs R6 duplicate-launch probe): loss_kernel = 47.2 us for
// 302 MB read-once = 6.40 TB/s = 95.5% of this chip's own fill BW
// (6.70 TB/s) -> at the HBM roofline. The remaining ~330 us of dur_us is
// per-iteration harness work (1.07 GB ws poison + input restore).

// Final reduce: 1024 doubles -> one float. One block of 256 threads.
__global__ void finalize_kernel(const double* __restrict__ partial,
                                float* __restrict__ out) {
    const int t = threadIdx.x;
    double c = (partial[t] + partial[t + 256]) +
               (partial[t + 512] + partial[t + 768]);
#pragma unroll
    for (int off = 32; off > 0; off >>= 1) c += __shfl_down(c, off, 64);
    __shared__ double wsum[4];
    const int lane = t & 63, wv = t >> 6;
    if (lane == 0) wsum[wv] = c;
    __syncthreads();
    if (t == 0) out[0] = (float)((wsum[0] + wsum[1]) + (wsum[2] + wsum[3]));
}

// Doolittle row-streaming LU (no pivoting; matrices are I + 0.1*noise,
// well-conditioned -> absmax 0.0 vs reference). Only the upper triangle
// stays live; explicit next-row prefetch keeps 16 loads in flight during
// elimination (~215 VGPRs, 2 waves/SIMD).
__global__ __launch_bounds__(256, 2) void loss_kernel(
    const float* __restrict__ gamma,
    const float* __restrict__ exp_cpv,
    const float* __restrict__ rmat,
    double* __restrict__ partial) {
    const int n = blockIdx.x * blockDim.x + threadIdx.x;

    // diff = gamma[n,:] - exp_cpv[n,:]  (contiguous 64B per thread, float4 x4)
    float diff[D];
    {
        const float4* g4 = reinterpret_cast<const float4*>(gamma + (size_t)n * D);
        const float4* e4 = reinterpret_cast<const float4*>(exp_cpv + (size_t)n * D);
#pragma unroll
        for (int c = 0; c < 4; ++c) {
            float4 g = g4[c];
            float4 e = e4[c];
            diff[4 * c + 0] = g.x - e.x;
            diff[4 * c + 1] = g.y - e.y;
            diff[4 * c + 2] = g.z - e.z;
            diff[4 * c + 3] = g.w - e.w;
        }
    }

    const float* Rb = rmat + n;

    float U[D][D];   // only j > i entries stay live (upper triangle)
    float invd[D];   // 1 / u_kk
    float vsq = 0.0f;      // sum v_i^2 (matvec with ORIGINAL rows)
    float detprod = 1.0f;  // product of pivots

    float a[D];      // current row (original values on entry to iteration i)
    float nxt[D];    // prefetched next row
#pragma unroll
    for (int j = 0; j < D; ++j) a[j] = Rb[(size_t)j * NSL];

#pragma unroll
    for (int i = 0; i < D; ++i) {
        // Issue next row's loads FIRST so they overlap the elimination math.
        if (i < D - 1) {
#pragma unroll
            for (int j = 0; j < D; ++j)
                nxt[j] = Rb[(size_t)((i + 1) * D + j) * NSL];
        }

        // Matvec with the ORIGINAL row before elimination destroys it.
        float vi = 0.0f;
#pragma unroll
        for (int j = 0; j < D; ++j) vi += a[j] * diff[j];
        vsq += vi * vi;

        // Fold row i against previously finalized U rows 0..i-1.
#pragma unroll
        for (int k = 0; k < i; ++k) {
            float m = a[k] * invd[k];
#pragma unroll
            for (int j = k + 1; j < D; ++j) a[j] -= m * U[k][j];
        }

        // Row i finalized: pivot is a[i].
        detprod *= a[i];
        invd[i] = 1.0f / a[i];
#pragma unroll
        for (int j = i + 1; j < D; ++j) U[i][j] = a[j];

        if (i < D - 1) {
#pragma unroll
            for (int j = 0; j < D; ++j) a[j] = nxt[j];
        }
    }

    const float l2 = sqrtf(vsq);
    const float logabs = logf(fabsf(detprod));
    double c = (double)l2 - 2.0 * (double)logabs;

    // Wave (64-lane) reduction, then one plain store per block (no atomic,
    // no ws zero-init needed: finalize reads exactly the written slots).
#pragma unroll
    for (int off = 32; off > 0; off >>= 1) c += __shfl_down(c, off, 64);

    __shared__ double wsum[4];
    const int lane = threadIdx.x & 63;
    const int wv = threadIdx.x >> 6;
    if (lane == 0) wsum[wv] = c;
    __syncthreads();
    if (threadIdx.x == 0) {
        partial[blockIdx.x] = (wsum[0] + wsum[1]) + (wsum[2] + wsum[3]);
    }
}

extern "C" void kernel_launch(void* const* d_in, const int* in_sizes, int n_in,
                              void* d_out, int out_size, void* d_ws, size_t ws_size,
                              hipStream_t stream) {
    const float* gamma = (const float*)d_in[0];
    const float* exp_cpv = (const float*)d_in[1];
    const float* rmat = (const float*)d_in[2];
    float* out = (float*)d_out;
    double* partial = (double*)d_ws;

    loss_kernel<<<NBLK, 256, 0, stream>>>(gamma, exp_cpv, rmat, partial);
    finalize_kernel<<<1, 256, 0, stream>>>(partial, out);
}